// Round 8
// baseline (574.536 us; speedup 1.0000x reference)
//
#include <hip/hip_runtime.h>
#include <hip/hip_cooperative_groups.h>

namespace cg = cooperative_groups;

// Problem constants: B=512, D=1024, H1=512, H2=128
// Outputs (f32, concat): recover [512,1024], c2 [512,128], Jac [512,128,1024]
//
// R8 vs R6 (404.3 best) / R7 (435, reverted):
//  - Single cooperative launch (512 blocks, 2/CU) replaces the 4-launch chain.
//    Phases via grid.sync(): P1 c1-GEMM||prep, P2 c2, P3 c3h, P4 recover+jac
//    (2080 units grid-strided, 4-5 sequential units/block -> stores overlap next
//    unit's staging; per-block constant n0 keeps W1T slice L2-hot).
//  - Unit guard = lgkmcnt(0)-only + raw s_barrier (stores NOT drained at unit entry).
//  - Inner loops (gemm_dev, prep_dev, jac G=2, recover) are R6-verbatim.
//  - Checked fallback to the exact R6 4-launch path if cooperative launch unsupported.

typedef _Float16 f16x8 __attribute__((ext_vector_type(8)));
typedef _Float16 f16x4 __attribute__((ext_vector_type(4)));
typedef float    f32x4 __attribute__((ext_vector_type(4)));
typedef float    f32x2 __attribute__((ext_vector_type(2)));

__device__ __forceinline__ void gld_lds16(const _Float16* src, _Float16* dst_wave_uniform) {
    __builtin_amdgcn_global_load_lds((const __attribute__((address_space(1))) unsigned int*)src,
                                     (__attribute__((address_space(3))) unsigned int*)dst_wave_uniform,
                                     16, 0, 0);
}

// ---------------- prep: W1 transpose->f16, W2 ->f16 ----------------
__device__ __forceinline__ void prep_dev(int bx, const float* __restrict__ W1,
                                         const float* __restrict__ W2,
                                         _Float16* __restrict__ W1T,
                                         _Float16* __restrict__ W2h) {
    if (bx < 512) {
        __shared__ float tile[32][33];
        int dt = (bx & 31) * 32, kt = (bx >> 5) * 32;
        int tx = threadIdx.x & 31, ty = threadIdx.x >> 5;  // 32 x 8
        __syncthreads();   // guard: tile[] may be in use by a previous prep unit
        #pragma unroll
        for (int r = 0; r < 32; r += 8)
            tile[ty + r][tx] = W1[(kt + ty + r) * 1024 + dt + tx];
        __syncthreads();
        #pragma unroll
        for (int r = 0; r < 32; r += 8)
            W1T[(size_t)(dt + ty + r) * 512 + kt + tx] = (_Float16)tile[tx][ty + r];
    } else {
        int i = (bx - 512) * 1024 + threadIdx.x * 4;  // 64 blocks cover 65536
        f32x4 v = *(const f32x4*)(W2 + i);
        f16x4 h;
        h.x = (_Float16)v.x; h.y = (_Float16)v.y; h.z = (_Float16)v.z; h.w = (_Float16)v.w;
        *(f16x4*)(W2h + i) = h;
    }
}

// ---------------- small fp32 GEMMs (accuracy-critical path) ----------------
// 32x64 tile, 256 threads, per-thread 2x4, BK=32, register-prefetch pipeline.
template <int EPI, bool TRANSB>
__device__ void gemm_dev(const float* __restrict__ A, const float* __restrict__ Bm,
                         const float* __restrict__ bias,
                         float* __restrict__ C, float* __restrict__ Cd,
                         _Float16* __restrict__ Ch,
                         int M, int N, int K, int m0, int n0) {
    __shared__ __align__(16) float As[32][34];
    __shared__ __align__(16) float Bs[32][68];
    const int tid = threadIdx.x, tx = tid & 15, ty = tid >> 4;
    const int ka  = tid & 31, ma  = tid >> 5;
    const int kbt = tid & 31, nbt = tid >> 5;
    const int nbf = tid & 63, kbf = tid >> 6;
    float acc[2][4] = {};
    float rA[4], rB[8];

    #pragma unroll
    for (int r = 0; r < 4; ++r) rA[r] = A[(size_t)(m0 + ma + 8 * r) * K + ka];
    if (TRANSB) {
        #pragma unroll
        for (int r = 0; r < 8; ++r) rB[r] = Bm[(size_t)(n0 + nbt + 8 * r) * K + kbt];
    } else {
        #pragma unroll
        for (int r = 0; r < 8; ++r) rB[r] = Bm[(size_t)(kbf + 4 * r) * N + n0 + nbf];
    }

    for (int k0 = 0; k0 < K; k0 += 32) {
        #pragma unroll
        for (int r = 0; r < 4; ++r) As[ka][ma + 8 * r] = rA[r];
        if (TRANSB) {
            #pragma unroll
            for (int r = 0; r < 8; ++r) Bs[kbt][nbt + 8 * r] = rB[r];
        } else {
            #pragma unroll
            for (int r = 0; r < 8; ++r) Bs[kbf + 4 * r][nbf] = rB[r];
        }
        const int k1 = k0 + 32;
        if (k1 < K) {
            #pragma unroll
            for (int r = 0; r < 4; ++r) rA[r] = A[(size_t)(m0 + ma + 8 * r) * K + k1 + ka];
            if (TRANSB) {
                #pragma unroll
                for (int r = 0; r < 8; ++r) rB[r] = Bm[(size_t)(n0 + nbt + 8 * r) * K + k1 + kbt];
            } else {
                #pragma unroll
                for (int r = 0; r < 8; ++r) rB[r] = Bm[(size_t)(k1 + kbf + 4 * r) * N + n0 + nbf];
            }
        }
        __syncthreads();
        #pragma unroll
        for (int k = 0; k < 32; ++k) {
            f32x2 av = *(const f32x2*)&As[k][ty * 2];
            f32x4 bv = *(const f32x4*)&Bs[k][tx * 4];
            #pragma unroll
            for (int i = 0; i < 2; ++i)
                #pragma unroll
                for (int j = 0; j < 4; ++j)
                    acc[i][j] += av[i] * bv[j];
        }
        __syncthreads();
    }

    #pragma unroll
    for (int i = 0; i < 2; ++i) {
        int row = m0 + ty * 2 + i;
        #pragma unroll
        for (int j = 0; j < 4; ++j) {
            int col = n0 + tx * 4 + j;
            float z = acc[i][j] + bias[col];
            float s = 1.f / (1.f + __expf(-z));
            if constexpr (EPI == 1) {
                C[(size_t)row * N + col]  = s;
                Cd[(size_t)row * N + col] = s * (1.f - s);
            } else {
                Ch[(size_t)row * N + col] = (_Float16)s;
            }
        }
    }
}

// ---------------- P4 units (shared buffers passed in; R6-verbatim bodies) ----------------
__device__ __forceinline__ void unit_guard() {
    // drain own LDS ops only (NOT vmcnt: previous unit's stores keep flying)
    asm volatile("s_waitcnt lgkmcnt(0)" ::: "memory");
    __builtin_amdgcn_sched_barrier(0);
    __builtin_amdgcn_s_barrier();
}

__device__ __forceinline__ void recover_unit(int u,
        _Float16* __restrict__ Wsl, _Float16* __restrict__ Bsl, float* __restrict__ S2s0,
        const _Float16* __restrict__ c3h, const _Float16* __restrict__ W1T,
        const float* __restrict__ br, float* __restrict__ out_rec) {
    const int tid = threadIdx.x;
    const int lane = tid & 63, wave = tid >> 6;
    const int wm = (wave >> 1) * 64, wn = (wave & 1) * 64;
    const int l15 = lane & 15, q = lane >> 4;
    const int srow = wave * 8 + (lane >> 3);
    const int skof = ((lane & 7) ^ (lane >> 3)) * 8;

    unit_guard();

    const int m0 = (u >> 3) * 128, n0 = (u & 7) * 128;
    const _Float16* Abase = c3h + (size_t)m0 * 512;
    const _Float16* Bbase = W1T + (size_t)n0 * 512;
    float* outp = out_rec + (size_t)m0 * 1024;
    if (tid < 128) S2s0[tid] = br[n0 + tid];

    f32x4 acc[4][4];
    #pragma unroll
    for (int i = 0; i < 4; ++i)
        #pragma unroll
        for (int j = 0; j < 4; ++j) acc[i][j] = (f32x4){0.f, 0.f, 0.f, 0.f};

    for (int t = 0; t < 8; ++t) {
        const int kb = t * 64;
        #pragma unroll
        for (int r = 0; r < 4; ++r) {
            gld_lds16(Abase + (size_t)(r * 32 + srow) * 512 + kb + skof, Wsl + (r * 32 + wave * 8) * 64);
            gld_lds16(Bbase + (size_t)(r * 32 + srow) * 512 + kb + skof, Bsl + (r * 32 + wave * 8) * 64);
        }
        __syncthreads();
        #pragma unroll
        for (int kk = 0; kk < 64; kk += 32) {
            f16x8 af[4], bf[4];
            #pragma unroll
            for (int i = 0; i < 4; ++i)
                af[i] = *(const f16x8*)(Wsl + (wm + i * 16 + l15) * 64 + ((kk + q * 8) ^ ((l15 & 7) * 8)));
            #pragma unroll
            for (int j = 0; j < 4; ++j)
                bf[j] = *(const f16x8*)(Bsl + (wn + j * 16 + l15) * 64 + ((kk + q * 8) ^ ((l15 & 7) * 8)));
            #pragma unroll
            for (int i = 0; i < 4; ++i)
                #pragma unroll
                for (int j = 0; j < 4; ++j)
                    acc[i][j] = __builtin_amdgcn_mfma_f32_16x16x32_f16(af[i], bf[j], acc[i][j], 0, 0, 0);
        }
        __syncthreads();
    }

    #pragma unroll
    for (int i = 0; i < 4; ++i) {
        #pragma unroll
        for (int rg = 0; rg < 4; ++rg) {
            int ml = wm + i * 16 + q * 4 + rg;
            #pragma unroll
            for (int j = 0; j < 4; ++j) {
                int cl = wn + j * 16 + l15;
                __builtin_nontemporal_store(acc[i][j][rg] + S2s0[cl],
                                            outp + (size_t)ml * 1024 + n0 + cl);
            }
        }
    }
}

__device__ __forceinline__ void jac_unit(int jid,
        _Float16* __restrict__ Wsl, _Float16* __restrict__ Bsl,
        _Float16 (*__restrict__ S1h)[512], float (*__restrict__ S2s)[128],
        const _Float16* __restrict__ W2h, const _Float16* __restrict__ W1T,
        const float* __restrict__ s1p, const float* __restrict__ s2p,
        float* __restrict__ out_jac) {
    const int tid = threadIdx.x;
    const int lane = tid & 63, wave = tid >> 6;
    const int wm = (wave >> 1) * 64, wn = (wave & 1) * 64;
    const int l15 = lane & 15, q = lane >> 4;
    const int srow = wave * 8 + (lane >> 3);
    const int skof = ((lane & 7) ^ (lane >> 3)) * 8;

    unit_guard();

    // direct map: per-block stride-512 units keep jid&7 (=n0) constant -> W1T slice L2-hot
    const int pair = jid >> 3, n0 = (jid & 7) * 128;
    const int bA = pair * 2;

    S1h[0][tid]       = (_Float16)s1p[(size_t)bA * 512 + tid];
    S1h[0][tid + 256] = (_Float16)s1p[(size_t)bA * 512 + 256 + tid];
    S1h[1][tid]       = (_Float16)s1p[(size_t)(bA + 1) * 512 + tid];
    S1h[1][tid + 256] = (_Float16)s1p[(size_t)(bA + 1) * 512 + 256 + tid];
    if (tid < 128) S2s[0][tid] = s2p[(size_t)bA * 128 + tid];
    else           S2s[1][tid - 128] = s2p[(size_t)(bA + 1) * 128 + (tid - 128)];

    const _Float16* Bbase = W1T + (size_t)n0 * 512;

    f32x4 accA[4][4], accB[4][4];
    #pragma unroll
    for (int i = 0; i < 4; ++i)
        #pragma unroll
        for (int j = 0; j < 4; ++j) {
            accA[i][j] = (f32x4){0.f, 0.f, 0.f, 0.f};
            accB[i][j] = (f32x4){0.f, 0.f, 0.f, 0.f};
        }

    for (int t = 0; t < 8; ++t) {
        const int kb = t * 64;
        #pragma unroll
        for (int r = 0; r < 4; ++r) {
            gld_lds16(W2h   + (size_t)(r * 32 + srow) * 512 + kb + skof, Wsl + (r * 32 + wave * 8) * 64);
            gld_lds16(Bbase + (size_t)(r * 32 + srow) * 512 + kb + skof, Bsl + (r * 32 + wave * 8) * 64);
        }
        __syncthreads();
        #pragma unroll
        for (int kk = 0; kk < 64; kk += 32) {
            const f16x8 sfA = *(const f16x8*)(&S1h[0][kb + kk + q * 8]);   // broadcast
            const f16x8 sfB = *(const f16x8*)(&S1h[1][kb + kk + q * 8]);
            f16x8 bf[4];
            #pragma unroll
            for (int j = 0; j < 4; ++j)
                bf[j] = *(const f16x8*)(Bsl + (wn + j * 16 + l15) * 64 + ((kk + q * 8) ^ ((l15 & 7) * 8)));
            #pragma unroll
            for (int i = 0; i < 4; ++i) {
                const f16x8 wf = *(const f16x8*)(Wsl + (wm + i * 16 + l15) * 64 + ((kk + q * 8) ^ ((l15 & 7) * 8)));
                f16x8 af = wf * sfA;                       // v_pk_mul_f16
                #pragma unroll
                for (int j = 0; j < 4; ++j)
                    accA[i][j] = __builtin_amdgcn_mfma_f32_16x16x32_f16(af, bf[j], accA[i][j], 0, 0, 0);
                af = wf * sfB;
                #pragma unroll
                for (int j = 0; j < 4; ++j)
                    accB[i][j] = __builtin_amdgcn_mfma_f32_16x16x32_f16(af, bf[j], accB[i][j], 0, 0, 0);
            }
        }
        __syncthreads();
    }

    float* outA = out_jac + (size_t)bA * (128 * 1024);
    float* outB = outA + (128 * 1024);
    #pragma unroll
    for (int i = 0; i < 4; ++i) {
        #pragma unroll
        for (int rg = 0; rg < 4; ++rg) {
            int ml = wm + i * 16 + q * 4 + rg;
            float rsA = S2s[0][ml], rsB = S2s[1][ml];
            #pragma unroll
            for (int j = 0; j < 4; ++j) {
                int cl = wn + j * 16 + l15;
                __builtin_nontemporal_store(accA[i][j][rg] * rsA, outA + (size_t)ml * 1024 + n0 + cl);
                __builtin_nontemporal_store(accB[i][j][rg] * rsB, outB + (size_t)ml * 1024 + n0 + cl);
            }
        }
    }
}

// ---------------- the single cooperative kernel ----------------
__global__ __launch_bounds__(256, 2) void mega_kernel(
        const float* __restrict__ x,  const float* __restrict__ W1, const float* __restrict__ b1,
        const float* __restrict__ W2, const float* __restrict__ b2, const float* __restrict__ b3,
        const float* __restrict__ br,
        _Float16* __restrict__ W1T, _Float16* __restrict__ W2h,
        float* __restrict__ c1, float* __restrict__ s1p, float* __restrict__ s2p,
        _Float16* __restrict__ c3h,
        float* __restrict__ out_rec, float* __restrict__ out_c2, float* __restrict__ out_jac) {
    __shared__ __align__(16) _Float16 Wsl[128 * 64];
    __shared__ __align__(16) _Float16 Bsl[128 * 64];
    __shared__ _Float16 S1h[2][512];
    __shared__ float    S2s[2][128];

    cg::grid_group grid = cg::this_grid();
    const int bid = blockIdx.x;

    // P1: c1 GEMM (128 blocks) || prep (384 blocks covering 576 units)
    if (bid < 128) {
        gemm_dev<1, true>(x, W1, b1, c1, s1p, nullptr, 512, 512, 1024,
                          (bid >> 3) * 32, (bid & 7) * 64);
    } else {
        int u = bid - 128;
        prep_dev(u, W1, W2, W1T, W2h);
        if (u + 384 < 576) prep_dev(u + 384, W1, W2, W1T, W2h);
    }
    grid.sync();

    // P2: c2 (+ s2p), 32 blocks
    if (bid < 32)
        gemm_dev<1, true>(c1, W2, b2, out_c2, s2p, nullptr, 512, 128, 512,
                          (bid >> 1) * 32, (bid & 1) * 64);
    grid.sync();

    // P3: c3h, 128 blocks
    if (bid < 128)
        gemm_dev<2, false>(out_c2, W2, b3, nullptr, nullptr, c3h, 512, 512, 128,
                           (bid >> 3) * 32, (bid & 7) * 64);
    grid.sync();

    // P4: 2080 units grid-strided (blocks 0..31 take 5 units, rest 4)
    for (int u = bid; u < 2080; u += 512) {
        if (u < 32) recover_unit(u, Wsl, Bsl, S2s[0], c3h, W1T, br, out_rec);
        else        jac_unit(u - 32, Wsl, Bsl, S1h, S2s, W2h, W1T, s1p, s2p, out_jac);
    }
}

// ---------------- fallback: exact R6 4-launch path ----------------
__global__ __launch_bounds__(256) void fused_prep_gemm1(const float* __restrict__ x,
                                                        const float* __restrict__ W1,
                                                        const float* __restrict__ b1,
                                                        const float* __restrict__ W2,
                                                        _Float16* __restrict__ W1T,
                                                        _Float16* __restrict__ W2h,
                                                        float* __restrict__ c1,
                                                        float* __restrict__ s1p) {
    int bx = blockIdx.x;
    if (bx < 128) {
        gemm_dev<1, true>(x, W1, b1, c1, s1p, nullptr, 512, 512, 1024,
                          (bx >> 3) * 32, (bx & 7) * 64);
    } else {
        prep_dev(bx - 128, W1, W2, W1T, W2h);
    }
}

__global__ __launch_bounds__(256) void gemm2_kernel(const float* __restrict__ c1,
                                                    const float* __restrict__ W2,
                                                    const float* __restrict__ b2,
                                                    float* __restrict__ out_c2,
                                                    float* __restrict__ s2p) {
    gemm_dev<1, true>(c1, W2, b2, out_c2, s2p, nullptr, 512, 128, 512,
                      blockIdx.y * 32, blockIdx.x * 64);
}

__global__ __launch_bounds__(256) void gemm3_kernel(const float* __restrict__ out_c2,
                                                    const float* __restrict__ W2,
                                                    const float* __restrict__ b3,
                                                    _Float16* __restrict__ c3h) {
    gemm_dev<2, false>(out_c2, W2, b3, nullptr, nullptr, c3h, 512, 512, 128,
                       (blockIdx.x >> 3) * 32, (blockIdx.x & 7) * 64);
}

__global__ __launch_bounds__(256, 2) void jacW_fused(const _Float16* __restrict__ c3h,
                                                     const _Float16* __restrict__ W2h,
                                                     const _Float16* __restrict__ W1T,
                                                     const float* __restrict__ s1p,
                                                     const float* __restrict__ s2p,
                                                     const float* __restrict__ br,
                                                     float* __restrict__ out_rec,
                                                     float* __restrict__ out_jac) {
    __shared__ __align__(16) _Float16 Wsl[128 * 64];
    __shared__ __align__(16) _Float16 Bsl[128 * 64];
    __shared__ _Float16 S1h[2][512];
    __shared__ float    S2s[2][128];

    const int bid = blockIdx.x;
    if (bid < 32) {
        recover_unit(bid, Wsl, Bsl, S2s[0], c3h, W1T, br, out_rec);
        return;
    }
    const int jid = bid - 32;
    const int w = (jid & 7) * 256 + (jid >> 3);   // XCD-chunked bijection (2048 = 8*256)
    jac_unit(w, Wsl, Bsl, S1h, S2s, W2h, W1T, s1p, s2p, out_jac);
}

extern "C" void kernel_launch(void* const* d_in, const int* in_sizes, int n_in,
                              void* d_out, int out_size, void* d_ws, size_t ws_size,
                              hipStream_t stream) {
    const float* x  = (const float*)d_in[0];
    const float* W1 = (const float*)d_in[1];
    const float* b1 = (const float*)d_in[2];
    const float* W2 = (const float*)d_in[3];
    const float* b2 = (const float*)d_in[4];
    const float* b3 = (const float*)d_in[5];
    const float* br = (const float*)d_in[6];

    float* out_rec = (float*)d_out;               // 512*1024
    float* out_c2  = out_rec + 512 * 1024;        // 512*128
    float* out_jac = out_c2 + 512 * 128;          // 512*128*1024

    char* ws = (char*)d_ws;
    _Float16* W1T = (_Float16*)(ws);               // 1 MB   [1024][512]
    _Float16* W2h = (_Float16*)(ws + 0x100000);    // 128 KB [128][512]
    float*    c1  = (float*)(ws + 0x120000);       // 1 MB
    float*    s1p = (float*)(ws + 0x220000);       // 1 MB
    float*    s2p = (float*)(ws + 0x320000);       // 256 KB
    _Float16* c3h = (_Float16*)(ws + 0x360000);    // 512 KB (ends 0x3E0000, ~3.9 MB total)

    int dev = 0, coop = 0;
    hipGetDevice(&dev);
    hipDeviceGetAttribute(&coop, hipDeviceAttributeCooperativeLaunch, dev);

    hipError_t lerr = hipErrorUnknown;
    if (coop) {
        void* args[] = {(void*)&x, (void*)&W1, (void*)&b1, (void*)&W2, (void*)&b2,
                        (void*)&b3, (void*)&br, (void*)&W1T, (void*)&W2h, (void*)&c1,
                        (void*)&s1p, (void*)&s2p, (void*)&c3h,
                        (void*)&out_rec, (void*)&out_c2, (void*)&out_jac};
        lerr = hipLaunchCooperativeKernel((const void*)mega_kernel, dim3(512), dim3(256),
                                          args, 0, stream);
    }
    if (lerr != hipSuccess) {
        (void)hipGetLastError();   // clear error state, fall back to R6 path
        fused_prep_gemm1<<<704, 256, 0, stream>>>(x, W1, b1, W2, W1T, W2h, c1, s1p);
        gemm2_kernel<<<dim3(2, 16), 256, 0, stream>>>(c1, W2, b2, out_c2, s2p);
        gemm3_kernel<<<128, 256, 0, stream>>>(out_c2, W2, b3, c3h);
        jacW_fused<<<2080, 256, 0, stream>>>(c3h, W2h, W1T, s1p, s2p, br, out_rec, out_jac);
    }
}

// Round 9
// 397.234 us; speedup vs baseline: 1.4463x; 1.4463x over previous
//
#include <hip/hip_runtime.h>

// Problem constants: B=512, D=1024, H1=512, H2=128
// Outputs (f32, concat): recover [512,1024], c2 [512,128], Jac [512,128,1024]
//
// R9 = R6 (404.3, best) + LDS-transpose epilogue on the jac path:
//  - Old epilogue stores 4x64B segments per instruction (half cache lines) -> ~3 TB/s
//    effective write BW vs 6.4 TB/s measured pure-write rate (fills). New epilogue
//    stages acc through padded Esl[64][132] f32, then stores 32 lanes x f32x4 =
//    512 B contiguous per row (full 128B lines only).
//  - Extra 33.8 KB LDS -> ~68 KB total, still 2 blocks/CU ((256,2) unchanged).
//  - Everything else (front chain, jac G=2 K-loop, recover, grids) R6-verbatim.

typedef _Float16 f16x8 __attribute__((ext_vector_type(8)));
typedef _Float16 f16x4 __attribute__((ext_vector_type(4)));
typedef float    f32x4 __attribute__((ext_vector_type(4)));
typedef float    f32x2 __attribute__((ext_vector_type(2)));

__device__ __forceinline__ void gld_lds16(const _Float16* src, _Float16* dst_wave_uniform) {
    __builtin_amdgcn_global_load_lds((const __attribute__((address_space(1))) unsigned int*)src,
                                     (__attribute__((address_space(3))) unsigned int*)dst_wave_uniform,
                                     16, 0, 0);
}

// ---------------- prep: W1 transpose->f16, W2 ->f16 ----------------
__device__ __forceinline__ void prep_dev(int bx, const float* __restrict__ W1,
                                         const float* __restrict__ W2,
                                         _Float16* __restrict__ W1T,
                                         _Float16* __restrict__ W2h) {
    if (bx < 512) {
        __shared__ float tile[32][33];
        int dt = (bx & 31) * 32, kt = (bx >> 5) * 32;
        int tx = threadIdx.x & 31, ty = threadIdx.x >> 5;  // 32 x 8
        #pragma unroll
        for (int r = 0; r < 32; r += 8)
            tile[ty + r][tx] = W1[(kt + ty + r) * 1024 + dt + tx];
        __syncthreads();
        #pragma unroll
        for (int r = 0; r < 32; r += 8)
            W1T[(size_t)(dt + ty + r) * 512 + kt + tx] = (_Float16)tile[tx][ty + r];
    } else {
        int i = (bx - 512) * 1024 + threadIdx.x * 4;  // 64 blocks cover 65536
        f32x4 v = *(const f32x4*)(W2 + i);
        f16x4 h;
        h.x = (_Float16)v.x; h.y = (_Float16)v.y; h.z = (_Float16)v.z; h.w = (_Float16)v.w;
        *(f16x4*)(W2h + i) = h;
    }
}

// ---------------- small fp32 GEMMs (accuracy-critical path) ----------------
// 32x64 tile, 256 threads, per-thread 2x4, BK=32, register-prefetch pipeline.
template <int EPI, bool TRANSB>
__device__ void gemm_dev(const float* __restrict__ A, const float* __restrict__ Bm,
                         const float* __restrict__ bias,
                         float* __restrict__ C, float* __restrict__ Cd,
                         _Float16* __restrict__ Ch,
                         int M, int N, int K, int m0, int n0) {
    __shared__ __align__(16) float As[32][34];
    __shared__ __align__(16) float Bs[32][68];
    const int tid = threadIdx.x, tx = tid & 15, ty = tid >> 4;
    const int ka  = tid & 31, ma  = tid >> 5;
    const int kbt = tid & 31, nbt = tid >> 5;
    const int nbf = tid & 63, kbf = tid >> 6;
    float acc[2][4] = {};
    float rA[4], rB[8];

    #pragma unroll
    for (int r = 0; r < 4; ++r) rA[r] = A[(size_t)(m0 + ma + 8 * r) * K + ka];
    if (TRANSB) {
        #pragma unroll
        for (int r = 0; r < 8; ++r) rB[r] = Bm[(size_t)(n0 + nbt + 8 * r) * K + kbt];
    } else {
        #pragma unroll
        for (int r = 0; r < 8; ++r) rB[r] = Bm[(size_t)(kbf + 4 * r) * N + n0 + nbf];
    }

    for (int k0 = 0; k0 < K; k0 += 32) {
        #pragma unroll
        for (int r = 0; r < 4; ++r) As[ka][ma + 8 * r] = rA[r];
        if (TRANSB) {
            #pragma unroll
            for (int r = 0; r < 8; ++r) Bs[kbt][nbt + 8 * r] = rB[r];
        } else {
            #pragma unroll
            for (int r = 0; r < 8; ++r) Bs[kbf + 4 * r][nbf] = rB[r];
        }
        const int k1 = k0 + 32;
        if (k1 < K) {
            #pragma unroll
            for (int r = 0; r < 4; ++r) rA[r] = A[(size_t)(m0 + ma + 8 * r) * K + k1 + ka];
            if (TRANSB) {
                #pragma unroll
                for (int r = 0; r < 8; ++r) rB[r] = Bm[(size_t)(n0 + nbt + 8 * r) * K + k1 + kbt];
            } else {
                #pragma unroll
                for (int r = 0; r < 8; ++r) rB[r] = Bm[(size_t)(k1 + kbf + 4 * r) * N + n0 + nbf];
            }
        }
        __syncthreads();
        #pragma unroll
        for (int k = 0; k < 32; ++k) {
            f32x2 av = *(const f32x2*)&As[k][ty * 2];
            f32x4 bv = *(const f32x4*)&Bs[k][tx * 4];
            #pragma unroll
            for (int i = 0; i < 2; ++i)
                #pragma unroll
                for (int j = 0; j < 4; ++j)
                    acc[i][j] += av[i] * bv[j];
        }
        __syncthreads();
    }

    #pragma unroll
    for (int i = 0; i < 2; ++i) {
        int row = m0 + ty * 2 + i;
        #pragma unroll
        for (int j = 0; j < 4; ++j) {
            int col = n0 + tx * 4 + j;
            float z = acc[i][j] + bias[col];
            float s = 1.f / (1.f + __expf(-z));
            if constexpr (EPI == 1) {
                C[(size_t)row * N + col]  = s;
                Cd[(size_t)row * N + col] = s * (1.f - s);
            } else {
                Ch[(size_t)row * N + col] = (_Float16)s;
            }
        }
    }
}

// ---------------- fused launch wrappers ----------------
__global__ __launch_bounds__(256) void fused_prep_gemm1(const float* __restrict__ x,
                                                        const float* __restrict__ W1,
                                                        const float* __restrict__ b1,
                                                        const float* __restrict__ W2,
                                                        _Float16* __restrict__ W1T,
                                                        _Float16* __restrict__ W2h,
                                                        float* __restrict__ c1,
                                                        float* __restrict__ s1p) {
    int bx = blockIdx.x;
    if (bx < 128) {
        gemm_dev<1, true>(x, W1, b1, c1, s1p, nullptr, 512, 512, 1024,
                          (bx >> 3) * 32, (bx & 7) * 64);
    } else {
        prep_dev(bx - 128, W1, W2, W1T, W2h);
    }
}

__global__ __launch_bounds__(256) void gemm2_kernel(const float* __restrict__ c1,
                                                    const float* __restrict__ W2,
                                                    const float* __restrict__ b2,
                                                    float* __restrict__ out_c2,
                                                    float* __restrict__ s2p) {
    gemm_dev<1, true>(c1, W2, b2, out_c2, s2p, nullptr, 512, 128, 512,
                      blockIdx.y * 32, blockIdx.x * 64);
}

__global__ __launch_bounds__(256) void gemm3_kernel(const float* __restrict__ out_c2,
                                                    const float* __restrict__ W2,
                                                    const float* __restrict__ b3,
                                                    _Float16* __restrict__ c3h) {
    gemm_dev<2, false>(out_c2, W2, b3, nullptr, nullptr, c3h, 512, 512, 128,
                       (blockIdx.x >> 3) * 32, (blockIdx.x & 7) * 64);
}

// ---------------- fused MFMA: recover (32 blocks) + Jac (2048 blocks, G=2) ----------
// jac:  block = 2 batches x one 128-wide n-tile; A-tile = W2h k-slice (L2-hot),
//       af = wf * s1p[b] in registers; s2p row-scale at LDS-stage time.
//       NEW: epilogue stages acc through Esl[64][132] f32 and stores 512 B/row
//       contiguous f32x4 (full-line writes) instead of 4x64B fragment segments.
// recover: Out = c3h @ W1T^T + br (M=512), direct-store epilogue (only 2 MB).
__global__ __launch_bounds__(256, 2) void jacW_fused(const _Float16* __restrict__ c3h,
                                                     const _Float16* __restrict__ W2h,
                                                     const _Float16* __restrict__ W1T,
                                                     const float* __restrict__ s1p,
                                                     const float* __restrict__ s2p,
                                                     const float* __restrict__ br,
                                                     float* __restrict__ out_rec,
                                                     float* __restrict__ out_jac) {
    __shared__ __align__(16) _Float16 Wsl[128 * 64];  // A-src tile (W2h slice or c3h rows)
    __shared__ __align__(16) _Float16 Bsl[128 * 64];  // W1T tile
    __shared__ __align__(16) float    Esl[64][132];   // epilogue transpose buffer (pad 132)
    __shared__ _Float16 S1h[2][512];                  // jac: s1p[bA], s1p[bA+1] as f16
    __shared__ float    S2s[2][128];                  // jac: s2p pair / rec: bias

    const int tid = threadIdx.x;
    const int lane = tid & 63, wave = tid >> 6;
    const int wm = (wave >> 1) * 64, wn = (wave & 1) * 64;
    const int l15 = lane & 15, q = lane >> 4;
    const int bid = blockIdx.x;

    // staging geometry (proven swizzle): row = r*32 + wave*8 + (lane>>3),
    // source k-slot = (lane&7)^(lane>>3); LDS dest linear. Read slot = (kk/8+q)^(row&7).
    const int srow = wave * 8 + (lane >> 3);
    const int skof = ((lane & 7) ^ (lane >> 3)) * 8;

    if (bid < 32) {
        // ---------------- recover path (R5/R6-verbatim) ----------------
        const int m0 = (bid >> 3) * 128, n0 = (bid & 7) * 128;
        const _Float16* Abase = c3h + (size_t)m0 * 512;
        const _Float16* Bbase = W1T + (size_t)n0 * 512;
        float* outp = out_rec + (size_t)m0 * 1024;
        if (tid < 128) S2s[0][tid] = br[n0 + tid];

        f32x4 acc[4][4];
        #pragma unroll
        for (int i = 0; i < 4; ++i)
            #pragma unroll
            for (int j = 0; j < 4; ++j) acc[i][j] = (f32x4){0.f, 0.f, 0.f, 0.f};

        for (int t = 0; t < 8; ++t) {
            const int kb = t * 64;
            #pragma unroll
            for (int r = 0; r < 4; ++r) {
                gld_lds16(Abase + (size_t)(r * 32 + srow) * 512 + kb + skof, Wsl + (r * 32 + wave * 8) * 64);
                gld_lds16(Bbase + (size_t)(r * 32 + srow) * 512 + kb + skof, Bsl + (r * 32 + wave * 8) * 64);
            }
            __syncthreads();
            #pragma unroll
            for (int kk = 0; kk < 64; kk += 32) {
                f16x8 af[4], bf[4];
                #pragma unroll
                for (int i = 0; i < 4; ++i)
                    af[i] = *(const f16x8*)(Wsl + (wm + i * 16 + l15) * 64 + ((kk + q * 8) ^ ((l15 & 7) * 8)));
                #pragma unroll
                for (int j = 0; j < 4; ++j)
                    bf[j] = *(const f16x8*)(Bsl + (wn + j * 16 + l15) * 64 + ((kk + q * 8) ^ ((l15 & 7) * 8)));
                #pragma unroll
                for (int i = 0; i < 4; ++i)
                    #pragma unroll
                    for (int j = 0; j < 4; ++j)
                        acc[i][j] = __builtin_amdgcn_mfma_f32_16x16x32_f16(af[i], bf[j], acc[i][j], 0, 0, 0);
            }
            __syncthreads();
        }

        #pragma unroll
        for (int i = 0; i < 4; ++i) {
            #pragma unroll
            for (int rg = 0; rg < 4; ++rg) {
                int ml = wm + i * 16 + q * 4 + rg;
                #pragma unroll
                for (int j = 0; j < 4; ++j) {
                    int cl = wn + j * 16 + l15;
                    __builtin_nontemporal_store(acc[i][j][rg] + S2s[0][cl],
                                                outp + (size_t)ml * 1024 + n0 + cl);
                }
            }
        }
        return;
    }

    // ---------------- jac path: G=2 batches per block ----------------
    const int jid = bid - 32;
    const int w = (jid & 7) * 256 + (jid >> 3);   // XCD-chunked bijection (2048 = 8*256)
    const int pair = w >> 3, n0 = (w & 7) * 128;
    const int bA = pair * 2;

    S1h[0][tid]       = (_Float16)s1p[(size_t)bA * 512 + tid];
    S1h[0][tid + 256] = (_Float16)s1p[(size_t)bA * 512 + 256 + tid];
    S1h[1][tid]       = (_Float16)s1p[(size_t)(bA + 1) * 512 + tid];
    S1h[1][tid + 256] = (_Float16)s1p[(size_t)(bA + 1) * 512 + 256 + tid];
    if (tid < 128) S2s[0][tid] = s2p[(size_t)bA * 128 + tid];
    else           S2s[1][tid - 128] = s2p[(size_t)(bA + 1) * 128 + (tid - 128)];

    const _Float16* Bbase = W1T + (size_t)n0 * 512;

    f32x4 accA[4][4], accB[4][4];
    #pragma unroll
    for (int i = 0; i < 4; ++i)
        #pragma unroll
        for (int j = 0; j < 4; ++j) {
            accA[i][j] = (f32x4){0.f, 0.f, 0.f, 0.f};
            accB[i][j] = (f32x4){0.f, 0.f, 0.f, 0.f};
        }

    for (int t = 0; t < 8; ++t) {
        const int kb = t * 64;
        #pragma unroll
        for (int r = 0; r < 4; ++r) {
            gld_lds16(W2h   + (size_t)(r * 32 + srow) * 512 + kb + skof, Wsl + (r * 32 + wave * 8) * 64);
            gld_lds16(Bbase + (size_t)(r * 32 + srow) * 512 + kb + skof, Bsl + (r * 32 + wave * 8) * 64);
        }
        __syncthreads();
        #pragma unroll
        for (int kk = 0; kk < 64; kk += 32) {
            const f16x8 sfA = *(const f16x8*)(&S1h[0][kb + kk + q * 8]);   // broadcast
            const f16x8 sfB = *(const f16x8*)(&S1h[1][kb + kk + q * 8]);
            f16x8 bf[4];
            #pragma unroll
            for (int j = 0; j < 4; ++j)
                bf[j] = *(const f16x8*)(Bsl + (wn + j * 16 + l15) * 64 + ((kk + q * 8) ^ ((l15 & 7) * 8)));
            #pragma unroll
            for (int i = 0; i < 4; ++i) {
                const f16x8 wf = *(const f16x8*)(Wsl + (wm + i * 16 + l15) * 64 + ((kk + q * 8) ^ ((l15 & 7) * 8)));
                f16x8 af = wf * sfA;                       // v_pk_mul_f16
                #pragma unroll
                for (int j = 0; j < 4; ++j)
                    accA[i][j] = __builtin_amdgcn_mfma_f32_16x16x32_f16(af, bf[j], accA[i][j], 0, 0, 0);
                af = wf * sfB;
                #pragma unroll
                for (int j = 0; j < 4; ++j)
                    accB[i][j] = __builtin_amdgcn_mfma_f32_16x16x32_f16(af, bf[j], accB[i][j], 0, 0, 0);
            }
        }
        __syncthreads();
    }

    // ---- epilogue: LDS transpose -> full-line coalesced stores ----
    float* outA = out_jac + (size_t)bA * (128 * 1024);
    float* outB = outA + (128 * 1024);
    #pragma unroll
    for (int bsel = 0; bsel < 2; ++bsel) {
        float* op = bsel ? outB : outA;
        #pragma unroll
        for (int half = 0; half < 2; ++half) {
            __syncthreads();                       // Esl free from previous section
            if ((wave >> 1) == half) {             // the 2 waves owning these 64 rows
                #pragma unroll
                for (int i = 0; i < 4; ++i) {
                    #pragma unroll
                    for (int rg = 0; rg < 4; ++rg) {
                        const int lr = i * 16 + q * 4 + rg;                 // local row 0..63
                        const float rs = bsel ? S2s[1][half * 64 + lr]
                                              : S2s[0][half * 64 + lr];
                        #pragma unroll
                        for (int j = 0; j < 4; ++j) {
                            const int cl = wn + j * 16 + l15;
                            Esl[lr][cl] = (bsel ? accB[i][j][rg] : accA[i][j][rg]) * rs;
                        }
                    }
                }
            }
            __syncthreads();
            // all 256 threads: 64 rows x 512 B, 32 lanes x f32x4 per row (full lines)
            #pragma unroll
            for (int p = 0; p < 8; ++p) {
                const int lr = p * 8 + (tid >> 5);
                const f32x4 v4 = *(const f32x4*)&Esl[lr][(tid & 31) * 4];
                __builtin_nontemporal_store(v4,
                    (f32x4*)(op + (size_t)(half * 64 + lr) * 1024 + n0 + (tid & 31) * 4));
            }
        }
    }
}

extern "C" void kernel_launch(void* const* d_in, const int* in_sizes, int n_in,
                              void* d_out, int out_size, void* d_ws, size_t ws_size,
                              hipStream_t stream) {
    const float* x  = (const float*)d_in[0];
    const float* W1 = (const float*)d_in[1];
    const float* b1 = (const float*)d_in[2];
    const float* W2 = (const float*)d_in[3];
    const float* b2 = (const float*)d_in[4];
    const float* b3 = (const float*)d_in[5];
    const float* br = (const float*)d_in[6];

    float* out_rec = (float*)d_out;               // 512*1024
    float* out_c2  = out_rec + 512 * 1024;        // 512*128
    float* out_jac = out_c2 + 512 * 128;          // 512*128*1024

    char* ws = (char*)d_ws;
    _Float16* W1T = (_Float16*)(ws);               // 1 MB   [1024][512]
    _Float16* W2h = (_Float16*)(ws + 0x100000);    // 128 KB [128][512]
    float*    c1  = (float*)(ws + 0x120000);       // 1 MB
    float*    s1p = (float*)(ws + 0x220000);       // 1 MB
    float*    s2p = (float*)(ws + 0x320000);       // 256 KB
    _Float16* c3h = (_Float16*)(ws + 0x360000);    // 512 KB (ends 0x3E0000, ~3.9 MB total)

    // L1: c1 GEMM (128 blocks) + prep (576 blocks)
    fused_prep_gemm1<<<704, 256, 0, stream>>>(x, W1, b1, W2, W1T, W2h, c1, s1p);
    // L2: c2 (+ s2p)
    gemm2_kernel<<<dim3(2, 16), 256, 0, stream>>>(c1, W2, b2, out_c2, s2p);
    // L3: c3h
    gemm3_kernel<<<128, 256, 0, stream>>>(out_c2, W2, b3, c3h);
    // L4: recover (32 blocks) + Jac (2048 blocks, G=2, full-line epilogue)
    jacW_fused<<<2080, 256, 0, stream>>>(c3h, W2h, W1T, s1p, s2p, br, out_rec, out_jac);
}

// Round 10
// 371.435 us; speedup vs baseline: 1.5468x; 1.0695x over previous
//
#include <hip/hip_runtime.h>

// Problem constants: B=512, D=1024, H1=512, H2=128
// Outputs (f32, concat): recover [512,1024], c2 [512,128], Jac [512,128,1024]
//
// R10 = R9 (397.2, best) + front-chain collapse:
//  - L2 (c2) and L3 (c3h) merged into ONE row-stripe kernel (mid_fused, 64 blocks,
//    8 batch-rows each): the mid-network is row-local (c3[m] <- c2[m] <- c1[m]),
//    so a block computes c2 -> s2p -> out_c2 -> c3h for its rows with no cross-block
//    deps. f32 VALU, identical arithmetic to the old gemm_dev path.
//  - Launches 4 -> 3 (L1 prep+c1 | L2' mid_fused | L4 recover+jac).
//  - L1 and L4 (R9's full-line-epilogue jacW_fused) are verbatim.

typedef _Float16 f16x8 __attribute__((ext_vector_type(8)));
typedef _Float16 f16x4 __attribute__((ext_vector_type(4)));
typedef float    f32x4 __attribute__((ext_vector_type(4)));
typedef float    f32x2 __attribute__((ext_vector_type(2)));

__device__ __forceinline__ void gld_lds16(const _Float16* src, _Float16* dst_wave_uniform) {
    __builtin_amdgcn_global_load_lds((const __attribute__((address_space(1))) unsigned int*)src,
                                     (__attribute__((address_space(3))) unsigned int*)dst_wave_uniform,
                                     16, 0, 0);
}

// ---------------- prep: W1 transpose->f16, W2 ->f16 ----------------
__device__ __forceinline__ void prep_dev(int bx, const float* __restrict__ W1,
                                         const float* __restrict__ W2,
                                         _Float16* __restrict__ W1T,
                                         _Float16* __restrict__ W2h) {
    if (bx < 512) {
        __shared__ float tile[32][33];
        int dt = (bx & 31) * 32, kt = (bx >> 5) * 32;
        int tx = threadIdx.x & 31, ty = threadIdx.x >> 5;  // 32 x 8
        #pragma unroll
        for (int r = 0; r < 32; r += 8)
            tile[ty + r][tx] = W1[(kt + ty + r) * 1024 + dt + tx];
        __syncthreads();
        #pragma unroll
        for (int r = 0; r < 32; r += 8)
            W1T[(size_t)(dt + ty + r) * 512 + kt + tx] = (_Float16)tile[tx][ty + r];
    } else {
        int i = (bx - 512) * 1024 + threadIdx.x * 4;  // 64 blocks cover 65536
        f32x4 v = *(const f32x4*)(W2 + i);
        f16x4 h;
        h.x = (_Float16)v.x; h.y = (_Float16)v.y; h.z = (_Float16)v.z; h.w = (_Float16)v.w;
        *(f16x4*)(W2h + i) = h;
    }
}

// ---------------- fp32 GEMM for c1 (accuracy-critical, K=1024) ----------------
// 32x64 tile, 256 threads, per-thread 2x4, BK=32, register-prefetch pipeline.
__device__ void gemm_c1(const float* __restrict__ A, const float* __restrict__ Bm,
                        const float* __restrict__ bias,
                        float* __restrict__ C, float* __restrict__ Cd,
                        int m0, int n0) {
    const int N = 512, K = 1024;
    __shared__ __align__(16) float As[32][34];
    __shared__ __align__(16) float Bs[32][68];
    const int tid = threadIdx.x, tx = tid & 15, ty = tid >> 4;
    const int ka  = tid & 31, ma  = tid >> 5;
    const int kbt = tid & 31, nbt = tid >> 5;
    float acc[2][4] = {};
    float rA[4], rB[8];

    #pragma unroll
    for (int r = 0; r < 4; ++r) rA[r] = A[(size_t)(m0 + ma + 8 * r) * K + ka];
    #pragma unroll
    for (int r = 0; r < 8; ++r) rB[r] = Bm[(size_t)(n0 + nbt + 8 * r) * K + kbt];

    for (int k0 = 0; k0 < K; k0 += 32) {
        #pragma unroll
        for (int r = 0; r < 4; ++r) As[ka][ma + 8 * r] = rA[r];
        #pragma unroll
        for (int r = 0; r < 8; ++r) Bs[kbt][nbt + 8 * r] = rB[r];
        const int k1 = k0 + 32;
        if (k1 < K) {
            #pragma unroll
            for (int r = 0; r < 4; ++r) rA[r] = A[(size_t)(m0 + ma + 8 * r) * K + k1 + ka];
            #pragma unroll
            for (int r = 0; r < 8; ++r) rB[r] = Bm[(size_t)(n0 + nbt + 8 * r) * K + k1 + kbt];
        }
        __syncthreads();
        #pragma unroll
        for (int k = 0; k < 32; ++k) {
            f32x2 av = *(const f32x2*)&As[k][ty * 2];
            f32x4 bv = *(const f32x4*)&Bs[k][tx * 4];
            #pragma unroll
            for (int i = 0; i < 2; ++i)
                #pragma unroll
                for (int j = 0; j < 4; ++j)
                    acc[i][j] += av[i] * bv[j];
        }
        __syncthreads();
    }

    #pragma unroll
    for (int i = 0; i < 2; ++i) {
        int row = m0 + ty * 2 + i;
        #pragma unroll
        for (int j = 0; j < 4; ++j) {
            int col = n0 + tx * 4 + j;
            float z = acc[i][j] + bias[col];
            float s = 1.f / (1.f + __expf(-z));
            C[(size_t)row * N + col]  = s;
            Cd[(size_t)row * N + col] = s * (1.f - s);
        }
    }
}

// ---------------- L1: c1 GEMM (128 blocks) + prep (576 blocks) ----------------
__global__ __launch_bounds__(256) void fused_prep_gemm1(const float* __restrict__ x,
                                                        const float* __restrict__ W1,
                                                        const float* __restrict__ b1,
                                                        const float* __restrict__ W2,
                                                        _Float16* __restrict__ W1T,
                                                        _Float16* __restrict__ W2h,
                                                        float* __restrict__ c1,
                                                        float* __restrict__ s1p) {
    int bx = blockIdx.x;
    if (bx < 128) {
        gemm_c1(x, W1, b1, c1, s1p, (bx >> 3) * 32, (bx & 7) * 64);
    } else {
        prep_dev(bx - 128, W1, W2, W1T, W2h);
    }
}

// ---------------- L2': fused c2 + s2p + out_c2 + c3h (row-stripe, 64 blocks) ----------
// Block owns 8 batch-rows. Phase A: c2[8][128] = sigmoid(c1rows @ W2^T + b2), write
// out_c2 + s2p, keep c2 in LDS. Phase B: c3h[8][512] = f16(sigmoid(c2 @ W2 + b3)).
// All f32 VALU; arithmetic identical to the old gemm_dev<1,true>/<2,false> path.
__global__ __launch_bounds__(256) void mid_fused(const float* __restrict__ c1,
                                                 const float* __restrict__ W2,
                                                 const float* __restrict__ b2,
                                                 const float* __restrict__ b3,
                                                 float* __restrict__ out_c2,
                                                 float* __restrict__ s2p,
                                                 _Float16* __restrict__ c3h) {
    __shared__ __align__(16) float C1L[8][512];   // 16 KB
    __shared__ float C2L[8][128];                 // 4 KB
    const int tid = threadIdx.x;
    const int m0 = blockIdx.x * 8;

    // stage c1 rows (linear copy: 1024 f32x4)
    {
        const f32x4* src = (const f32x4*)(c1 + (size_t)m0 * 512);
        f32x4* dst = (f32x4*)&C1L[0][0];
        #pragma unroll
        for (int u = 0; u < 4; ++u) dst[tid + u * 256] = src[tid + u * 256];
    }
    __syncthreads();

    // Phase A: c2. thread -> (h = tid&127, row group rg = tid>>7 covering rows rg*4..+3)
    {
        const int h = tid & 127, rg = tid >> 7;
        const float* w2r = W2 + (size_t)h * 512;
        float acc[4] = {0.f, 0.f, 0.f, 0.f};
        for (int k = 0; k < 512; k += 4) {
            const f32x4 wv = *(const f32x4*)(w2r + k);
            #pragma unroll
            for (int r = 0; r < 4; ++r) {
                const f32x4 cv = *(const f32x4*)&C1L[rg * 4 + r][k];
                acc[r] += cv.x * wv.x + cv.y * wv.y + cv.z * wv.z + cv.w * wv.w;
            }
        }
        const float bb = b2[h];
        #pragma unroll
        for (int r = 0; r < 4; ++r) {
            const int row = rg * 4 + r;
            const float s = 1.f / (1.f + __expf(-(acc[r] + bb)));
            out_c2[(size_t)(m0 + row) * 128 + h] = s;
            s2p[(size_t)(m0 + row) * 128 + h]    = s * (1.f - s);
            C2L[row][h] = s;
        }
    }
    __syncthreads();

    // Phase B: c3h. thread -> cols j0 = tid, j1 = tid + 256; all 8 rows.
    {
        const int j0 = tid, j1 = tid + 256;
        float a0[8] = {}, a1[8] = {};
        for (int h = 0; h < 128; ++h) {
            const float w0 = W2[(size_t)h * 512 + j0];
            const float w1 = W2[(size_t)h * 512 + j1];
            #pragma unroll
            for (int r = 0; r < 8; ++r) {
                const float c = C2L[r][h];
                a0[r] += c * w0;
                a1[r] += c * w1;
            }
        }
        const float bb0 = b3[j0], bb1 = b3[j1];
        #pragma unroll
        for (int r = 0; r < 8; ++r) {
            c3h[(size_t)(m0 + r) * 512 + j0] = (_Float16)(1.f / (1.f + __expf(-(a0[r] + bb0))));
            c3h[(size_t)(m0 + r) * 512 + j1] = (_Float16)(1.f / (1.f + __expf(-(a1[r] + bb1))));
        }
    }
}

// ---------------- L4: recover (32 blocks) + Jac (2048 blocks, G=2) — R9-verbatim ------
__global__ __launch_bounds__(256, 2) void jacW_fused(const _Float16* __restrict__ c3h,
                                                     const _Float16* __restrict__ W2h,
                                                     const _Float16* __restrict__ W1T,
                                                     const float* __restrict__ s1p,
                                                     const float* __restrict__ s2p,
                                                     const float* __restrict__ br,
                                                     float* __restrict__ out_rec,
                                                     float* __restrict__ out_jac) {
    __shared__ __align__(16) _Float16 Wsl[128 * 64];  // A-src tile (W2h slice or c3h rows)
    __shared__ __align__(16) _Float16 Bsl[128 * 64];  // W1T tile
    __shared__ __align__(16) float    Esl[64][132];   // epilogue transpose buffer (pad 132)
    __shared__ _Float16 S1h[2][512];                  // jac: s1p[bA], s1p[bA+1] as f16
    __shared__ float    S2s[2][128];                  // jac: s2p pair / rec: bias

    const int tid = threadIdx.x;
    const int lane = tid & 63, wave = tid >> 6;
    const int wm = (wave >> 1) * 64, wn = (wave & 1) * 64;
    const int l15 = lane & 15, q = lane >> 4;
    const int bid = blockIdx.x;

    const int srow = wave * 8 + (lane >> 3);
    const int skof = ((lane & 7) ^ (lane >> 3)) * 8;

    if (bid < 32) {
        // ---------------- recover path ----------------
        const int m0 = (bid >> 3) * 128, n0 = (bid & 7) * 128;
        const _Float16* Abase = c3h + (size_t)m0 * 512;
        const _Float16* Bbase = W1T + (size_t)n0 * 512;
        float* outp = out_rec + (size_t)m0 * 1024;
        if (tid < 128) S2s[0][tid] = br[n0 + tid];

        f32x4 acc[4][4];
        #pragma unroll
        for (int i = 0; i < 4; ++i)
            #pragma unroll
            for (int j = 0; j < 4; ++j) acc[i][j] = (f32x4){0.f, 0.f, 0.f, 0.f};

        for (int t = 0; t < 8; ++t) {
            const int kb = t * 64;
            #pragma unroll
            for (int r = 0; r < 4; ++r) {
                gld_lds16(Abase + (size_t)(r * 32 + srow) * 512 + kb + skof, Wsl + (r * 32 + wave * 8) * 64);
                gld_lds16(Bbase + (size_t)(r * 32 + srow) * 512 + kb + skof, Bsl + (r * 32 + wave * 8) * 64);
            }
            __syncthreads();
            #pragma unroll
            for (int kk = 0; kk < 64; kk += 32) {
                f16x8 af[4], bf[4];
                #pragma unroll
                for (int i = 0; i < 4; ++i)
                    af[i] = *(const f16x8*)(Wsl + (wm + i * 16 + l15) * 64 + ((kk + q * 8) ^ ((l15 & 7) * 8)));
                #pragma unroll
                for (int j = 0; j < 4; ++j)
                    bf[j] = *(const f16x8*)(Bsl + (wn + j * 16 + l15) * 64 + ((kk + q * 8) ^ ((l15 & 7) * 8)));
                #pragma unroll
                for (int i = 0; i < 4; ++i)
                    #pragma unroll
                    for (int j = 0; j < 4; ++j)
                        acc[i][j] = __builtin_amdgcn_mfma_f32_16x16x32_f16(af[i], bf[j], acc[i][j], 0, 0, 0);
            }
            __syncthreads();
        }

        #pragma unroll
        for (int i = 0; i < 4; ++i) {
            #pragma unroll
            for (int rg = 0; rg < 4; ++rg) {
                int ml = wm + i * 16 + q * 4 + rg;
                #pragma unroll
                for (int j = 0; j < 4; ++j) {
                    int cl = wn + j * 16 + l15;
                    __builtin_nontemporal_store(acc[i][j][rg] + S2s[0][cl],
                                                outp + (size_t)ml * 1024 + n0 + cl);
                }
            }
        }
        return;
    }

    // ---------------- jac path: G=2 batches per block ----------------
    const int jid = bid - 32;
    const int w = (jid & 7) * 256 + (jid >> 3);   // XCD-chunked bijection (2048 = 8*256)
    const int pair = w >> 3, n0 = (w & 7) * 128;
    const int bA = pair * 2;

    S1h[0][tid]       = (_Float16)s1p[(size_t)bA * 512 + tid];
    S1h[0][tid + 256] = (_Float16)s1p[(size_t)bA * 512 + 256 + tid];
    S1h[1][tid]       = (_Float16)s1p[(size_t)(bA + 1) * 512 + tid];
    S1h[1][tid + 256] = (_Float16)s1p[(size_t)(bA + 1) * 512 + 256 + tid];
    if (tid < 128) S2s[0][tid] = s2p[(size_t)bA * 128 + tid];
    else           S2s[1][tid - 128] = s2p[(size_t)(bA + 1) * 128 + (tid - 128)];

    const _Float16* Bbase = W1T + (size_t)n0 * 512;

    f32x4 accA[4][4], accB[4][4];
    #pragma unroll
    for (int i = 0; i < 4; ++i)
        #pragma unroll
        for (int j = 0; j < 4; ++j) {
            accA[i][j] = (f32x4){0.f, 0.f, 0.f, 0.f};
            accB[i][j] = (f32x4){0.f, 0.f, 0.f, 0.f};
        }

    for (int t = 0; t < 8; ++t) {
        const int kb = t * 64;
        #pragma unroll
        for (int r = 0; r < 4; ++r) {
            gld_lds16(W2h   + (size_t)(r * 32 + srow) * 512 + kb + skof, Wsl + (r * 32 + wave * 8) * 64);
            gld_lds16(Bbase + (size_t)(r * 32 + srow) * 512 + kb + skof, Bsl + (r * 32 + wave * 8) * 64);
        }
        __syncthreads();
        #pragma unroll
        for (int kk = 0; kk < 64; kk += 32) {
            const f16x8 sfA = *(const f16x8*)(&S1h[0][kb + kk + q * 8]);   // broadcast
            const f16x8 sfB = *(const f16x8*)(&S1h[1][kb + kk + q * 8]);
            f16x8 bf[4];
            #pragma unroll
            for (int j = 0; j < 4; ++j)
                bf[j] = *(const f16x8*)(Bsl + (wn + j * 16 + l15) * 64 + ((kk + q * 8) ^ ((l15 & 7) * 8)));
            #pragma unroll
            for (int i = 0; i < 4; ++i) {
                const f16x8 wf = *(const f16x8*)(Wsl + (wm + i * 16 + l15) * 64 + ((kk + q * 8) ^ ((l15 & 7) * 8)));
                f16x8 af = wf * sfA;                       // v_pk_mul_f16
                #pragma unroll
                for (int j = 0; j < 4; ++j)
                    accA[i][j] = __builtin_amdgcn_mfma_f32_16x16x32_f16(af, bf[j], accA[i][j], 0, 0, 0);
                af = wf * sfB;
                #pragma unroll
                for (int j = 0; j < 4; ++j)
                    accB[i][j] = __builtin_amdgcn_mfma_f32_16x16x32_f16(af, bf[j], accB[i][j], 0, 0, 0);
            }
        }
        __syncthreads();
    }

    // ---- epilogue: LDS transpose -> full-line coalesced stores ----
    float* outA = out_jac + (size_t)bA * (128 * 1024);
    float* outB = outA + (128 * 1024);
    #pragma unroll
    for (int bsel = 0; bsel < 2; ++bsel) {
        float* op = bsel ? outB : outA;
        #pragma unroll
        for (int half = 0; half < 2; ++half) {
            __syncthreads();                       // Esl free from previous section
            if ((wave >> 1) == half) {             // the 2 waves owning these 64 rows
                #pragma unroll
                for (int i = 0; i < 4; ++i) {
                    #pragma unroll
                    for (int rg = 0; rg < 4; ++rg) {
                        const int lr = i * 16 + q * 4 + rg;                 // local row 0..63
                        const float rs = bsel ? S2s[1][half * 64 + lr]
                                              : S2s[0][half * 64 + lr];
                        #pragma unroll
                        for (int j = 0; j < 4; ++j) {
                            const int cl = wn + j * 16 + l15;
                            Esl[lr][cl] = (bsel ? accB[i][j][rg] : accA[i][j][rg]) * rs;
                        }
                    }
                }
            }
            __syncthreads();
            // all 256 threads: 64 rows x 512 B, 32 lanes x f32x4 per row (full lines)
            #pragma unroll
            for (int p = 0; p < 8; ++p) {
                const int lr = p * 8 + (tid >> 5);
                const f32x4 v4 = *(const f32x4*)&Esl[lr][(tid & 31) * 4];
                __builtin_nontemporal_store(v4,
                    (f32x4*)(op + (size_t)(half * 64 + lr) * 1024 + n0 + (tid & 31) * 4));
            }
        }
    }
}

extern "C" void kernel_launch(void* const* d_in, const int* in_sizes, int n_in,
                              void* d_out, int out_size, void* d_ws, size_t ws_size,
                              hipStream_t stream) {
    const float* x  = (const float*)d_in[0];
    const float* W1 = (const float*)d_in[1];
    const float* b1 = (const float*)d_in[2];
    const float* W2 = (const float*)d_in[3];
    const float* b2 = (const float*)d_in[4];
    const float* b3 = (const float*)d_in[5];
    const float* br = (const float*)d_in[6];

    float* out_rec = (float*)d_out;               // 512*1024
    float* out_c2  = out_rec + 512 * 1024;        // 512*128
    float* out_jac = out_c2 + 512 * 128;          // 512*128*1024

    char* ws = (char*)d_ws;
    _Float16* W1T = (_Float16*)(ws);               // 1 MB   [1024][512]
    _Float16* W2h = (_Float16*)(ws + 0x100000);    // 128 KB [128][512]
    float*    c1  = (float*)(ws + 0x120000);       // 1 MB
    float*    s1p = (float*)(ws + 0x220000);       // 1 MB
    float*    s2p = (float*)(ws + 0x320000);       // 256 KB
    _Float16* c3h = (_Float16*)(ws + 0x360000);    // 512 KB (ends 0x3E0000, ~3.9 MB total)

    // L1: c1 GEMM (128 blocks) + prep (576 blocks)
    fused_prep_gemm1<<<704, 256, 0, stream>>>(x, W1, b1, W2, W1T, W2h, c1, s1p);
    // L2': fused c2 + s2p + out_c2 + c3h (64 row-stripe blocks)
    mid_fused<<<64, 256, 0, stream>>>(c1, W2, b2, b3, out_c2, s2p, c3h);
    // L4: recover (32 blocks) + Jac (2048 blocks, G=2, full-line epilogue)
    jacW_fused<<<2080, 256, 0, stream>>>(c3h, W2h, W1T, s1p, s2p, br, out_rec, out_jac);
}